// Round 1
// baseline (1641.235 us; speedup 1.0000x reference)
//
#include <hip/hip_runtime.h>
#include <math.h>

// Problem constants
constexpr int kB   = 2;
constexpr int kF   = 257;   // FQ
constexpr int kT   = 100;
constexpr int kH   = 96;
constexpr int kS   = 8;
constexpr int kD   = 192;   // DIN
constexpr int kN   = 16;
constexpr int kR   = 6;
constexpr int kKF  = 5;
constexpr int kKM  = 4;
constexpr int kG   = 8;     // GROUPS
constexpr int kGC  = kH / kG;        // 12
constexpr int kBM  = kB * kF;        // 514
constexpr int kROWS = kB * kF * kT;  // 51400
constexpr int kNX  = kROWS * kH;     // 4,934,400
constexpr int kNM  = kBM * kT * kD;  // 9,868,800
constexpr int kDBL = kR + 2 * kN;    // 38

static_assert(kROWS % 8 == 0, "row tiling");

__device__ inline float wave_reduce_sum(float v) {
    for (int o = 32; o > 0; o >>= 1) v += __shfl_xor(v, o, 64);
    return v;
}
__device__ inline float silu_f(float x) { return x / (1.f + __expf(-x)); }
__device__ inline float softplus_f(float x) { return x > 20.f ? x : log1pf(__expf(x)); }

// ---------------- LayerNorm over H=96, one wave per row ----------------
__global__ void ln_kernel(const float* __restrict__ in, float* __restrict__ out,
                          const float* __restrict__ g, const float* __restrict__ b,
                          int rows) {
    int wave = threadIdx.x >> 6;
    int lane = threadIdx.x & 63;
    int r = blockIdx.x * 4 + wave;
    if (r >= rows) return;
    const float* p = in + (size_t)r * kH;
    float v0 = p[lane];
    float v1 = (lane < 32) ? p[64 + lane] : 0.f;
    float s = wave_reduce_sum(v0 + v1);
    float mean = s * (1.f / 96.f);
    float d0 = v0 - mean;
    float d1 = (lane < 32) ? (v1 - mean) : 0.f;
    float vs = wave_reduce_sum(d0 * d0 + d1 * d1);
    float rstd = rsqrtf(vs * (1.f / 96.f) + 1e-5f);
    float* q = out + (size_t)r * kH;
    q[lane] = d0 * rstd * g[lane] + b[lane];
    if (lane < 32) q[64 + lane] = d1 * rstd * g[64 + lane] + b[64 + lane];
}

// ---------------- freq-conv stage: grouped conv over F + PReLU + residual ----------------
__global__ void fconv_kernel(const float* __restrict__ ln, const float* __restrict__ resid,
                             float* __restrict__ out, const float* __restrict__ w,
                             const float* __restrict__ cb, const float* __restrict__ alpha) {
    __shared__ float wl[kGC * kKF * kH];  // transposed: [(ci*kKF+k)*kH + h]
    for (int i = threadIdx.x; i < kH * kGC * kKF; i += blockDim.x) {
        int h = i / (kGC * kKF);
        int rem = i % (kGC * kKF);
        wl[rem * kH + h] = w[i];
    }
    __syncthreads();
    int idx = blockIdx.x * blockDim.x + threadIdx.x;
    if (idx >= kNX) return;
    int h = idx % kH;
    int t = (idx / kH) % kT;
    int f = (idx / (kH * kT)) % kF;
    int b = idx / (kH * kT * kF);
    int g = h / kGC;
    float acc = cb[h];
    for (int k = 0; k < kKF; k++) {
        int fs = f + k - 2;
        if (fs < 0 || fs >= kF) continue;
        const float* src = ln + ((size_t)(b * kF + fs) * kT + t) * kH + g * kGC;
        for (int ci = 0; ci < kGC; ci++)
            acc += src[ci] * wl[(ci * kKF + k) * kH + h];
    }
    float y = acc > 0.f ? acc : alpha[h] * acc;
    out[idx] = resid[idx] + y;
}

// ---------------- full stage: squeeze H->S with SiLU ----------------
__global__ void squeeze_kernel(const float* __restrict__ ln, float* __restrict__ s1,
                               const float* __restrict__ sqw, const float* __restrict__ sqb) {
    int bt = blockIdx.x;                       // 0..199  (b*kT + t)
    int f = blockIdx.y * 64 + threadIdx.x;
    if (f >= kF) return;
    int b = bt / kT, t = bt % kT;
    const float* row = ln + ((size_t)(b * kF + f) * kT + t) * kH;
    float acc[kS];
    for (int s = 0; s < kS; s++) acc[s] = 0.f;
    for (int h = 0; h < kH; h++) {
        float v = row[h];
        for (int s = 0; s < kS; s++) acc[s] += v * sqw[s * kH + h];
    }
    for (int s = 0; s < kS; s++)
        s1[((size_t)bt * kS + s) * kF + f] = silu_f(acc[s] + sqb[s]);
}

// ---------------- full stage: per-group 257x257 matmul over F ----------------
__global__ void fullmat_kernel(const float* __restrict__ s1, float* __restrict__ s2,
                               const float* __restrict__ fw, const float* __restrict__ fb) {
    int bt = blockIdx.x, g = blockIdx.y;
    const float* srow = s1 + ((size_t)bt * kS + g) * kF;
    for (int k = threadIdx.x; k < kF; k += blockDim.x) {
        const float* wrow = fw + ((size_t)g * kF + k) * kF;
        float acc = fb[g * kF + k];
        for (int f = 0; f < kF; f++) acc += srow[f] * wrow[f];
        s2[((size_t)bt * kS + g) * kF + k] = acc;
    }
}

// ---------------- full stage: unsqueeze S->H + SiLU + residual (in-place on x) ----------------
__global__ void unsqueeze_kernel(const float* __restrict__ s2, float* __restrict__ x,
                                 const float* __restrict__ uw, const float* __restrict__ ub) {
    int idx = blockIdx.x * blockDim.x + threadIdx.x;
    if (idx >= kNX) return;
    int h = idx % kH;
    int t = (idx / kH) % kT;
    int f = (idx / (kH * kT)) % kF;
    int b = idx / (kH * kT * kF);
    int bt = b * kT + t;
    float acc = ub[h];
    for (int s = 0; s < kS; s++)
        acc += s2[((size_t)bt * kS + s) * kF + f] * uw[h * kS + s];
    x[idx] += silu_f(acc);
}

// ---------------- small weight transpose: in (rows,cols) -> out (cols,rows) ----------------
__global__ void transpose_kernel(const float* __restrict__ in, float* __restrict__ out,
                                 int rows, int cols) {
    int idx = blockIdx.x * blockDim.x + threadIdx.x;
    if (idx >= rows * cols) return;
    int r = idx / cols, c = idx % cols;
    out[c * rows + r] = in[idx];
}

// ---------------- mamba in-proj: xz = xn @ in_w.T  (384 outs), 8 rows per block ----------------
__global__ void inproj_kernel(const float* __restrict__ xn, const float* __restrict__ wT,
                              float* __restrict__ xin, float* __restrict__ z, int dir) {
    __shared__ float A[8 * kH];
    int r0 = blockIdx.x * 8;
    int tid = threadIdx.x;  // 0..383
    for (int p = tid; p < 8 * kH; p += 384) {
        int m = p / kH, h = p % kH;
        int r = r0 + m;
        int bm = r / kT, tl = r % kT;
        int srow = bm * kT + (dir ? (kT - 1 - tl) : tl);
        A[p] = xn[(size_t)srow * kH + h];
    }
    __syncthreads();
    float acc[8];
    for (int m = 0; m < 8; m++) acc[m] = 0.f;
    for (int h = 0; h < kH; h++) {
        float bv = wT[h * (2 * kD) + tid];
        for (int m = 0; m < 8; m++) acc[m] += A[m * kH + h] * bv;
    }
    for (int m = 0; m < 8; m++) {
        int r = r0 + m;
        if (tid < kD) xin[(size_t)r * kD + tid] = acc[m];
        else          z[(size_t)r * kD + (tid - kD)] = acc[m];
    }
}

// ---------------- mamba depthwise causal conv over T + SiLU ----------------
__global__ void mconv_kernel(const float* __restrict__ xin, float* __restrict__ xc,
                             const float* __restrict__ cw, const float* __restrict__ cb) {
    int idx = blockIdx.x * blockDim.x + threadIdx.x;
    if (idx >= kNM) return;
    int d = idx % kD;
    int t = (idx / kD) % kT;
    int bm = idx / (kD * kT);
    float acc = cb[d];
    for (int k = 0; k < kKM; k++) {
        int ts = t + k - (kKM - 1);
        if (ts >= 0) acc += xin[((size_t)bm * kT + ts) * kD + d] * cw[d * kKM + k];
    }
    xc[idx] = silu_f(acc);
}

// ---------------- mamba x-proj: dbl = xc @ xp_w.T (38 outs), one wave per row ----------------
__global__ void xpproj_kernel(const float* __restrict__ xc, float* __restrict__ dbl,
                              const float* __restrict__ wT) {
    int wave = threadIdx.x >> 6, lane = threadIdx.x & 63;
    int r = blockIdx.x * 4 + wave;
    if (r >= kROWS) return;
    if (lane >= kDBL) return;
    const float* row = xc + (size_t)r * kD;
    float acc = 0.f;
    for (int k = 0; k < kD; k++) acc += row[k] * wT[k * kDBL + lane];
    dbl[(size_t)r * kDBL + lane] = acc;
}

// ---------------- mamba selective scan: one thread per (bm, d), state in regs ----------------
// xcy holds xc on input; overwritten in place with ymid = (y + xc*D) * silu(z)
__global__ void scan_kernel(const float* __restrict__ dbl, const float* __restrict__ z,
                            float* __restrict__ xcy,
                            const float* __restrict__ A_log, const float* __restrict__ dtw,
                            const float* __restrict__ dtb, const float* __restrict__ Dp) {
    int bm = blockIdx.x;
    int d = threadIdx.x;
    float A[kN], hst[kN], dw[kR];
    for (int n = 0; n < kN; n++) { A[n] = -__expf(A_log[d * kN + n]); hst[n] = 0.f; }
    for (int r = 0; r < kR; r++) dw[r] = dtw[d * kR + r];
    float db = dtb[d], Dv = Dp[d];
    for (int t = 0; t < kT; t++) {
        size_t rb = (size_t)(bm * kT + t);
        const float* dr = dbl + rb * kDBL;
        float s = db;
        for (int r = 0; r < kR; r++) s += dr[r] * dw[r];
        float dt = softplus_f(s);
        float xv = xcy[rb * kD + d];
        float dtx = dt * xv;
        float y = 0.f;
        for (int n = 0; n < kN; n++) {
            hst[n] = __expf(dt * A[n]) * hst[n] + dtx * dr[kR + n];
            y += hst[n] * dr[kR + kN + n];
        }
        float zv = z[rb * kD + d];
        xcy[rb * kD + d] = (y + xv * Dv) * silu_f(zv);
    }
}

// ---------------- mamba out-proj + final combine ----------------
// dir==0: out[idx] = xres[idx] + 0.5*proj ; dir==1: out[idx(fliptime)] += 0.5*proj
__global__ void outproj_kernel(const float* __restrict__ ym, const float* __restrict__ wT,
                               const float* __restrict__ xres, float* __restrict__ out, int dir) {
    __shared__ float Y[8 * kD];
    int r0 = blockIdx.x * 8;
    int tid = threadIdx.x;  // 128
    for (int p = tid; p < 8 * kD; p += 128)
        Y[p] = ym[(size_t)r0 * kD + p];
    __syncthreads();
    if (tid >= kH) return;
    float acc[8];
    for (int m = 0; m < 8; m++) acc[m] = 0.f;
    for (int d = 0; d < kD; d++) {
        float wv = wT[d * kH + tid];
        for (int m = 0; m < 8; m++) acc[m] += Y[m * kD + d] * wv;
    }
    for (int m = 0; m < 8; m++) {
        int r = r0 + m;
        int bm = r / kT, tl = r % kT;
        int t = dir ? (kT - 1 - tl) : tl;
        size_t idx = ((size_t)bm * kT + t) * kH + tid;
        if (dir) out[idx] += 0.5f * acc[m];
        else     out[idx] = xres[idx] + 0.5f * acc[m];
    }
}

extern "C" void kernel_launch(void* const* d_in, const int* in_sizes, int n_in,
                              void* d_out, int out_size, void* d_ws, size_t ws_size,
                              hipStream_t stream) {
    const float* x       = (const float*)d_in[0];
    const float* ln1_g   = (const float*)d_in[1];
    const float* ln1_b   = (const float*)d_in[2];
    const float* conv1_w = (const float*)d_in[3];
    const float* conv1_b = (const float*)d_in[4];
    const float* prelu1  = (const float*)d_in[5];
    const float* lnf_g   = (const float*)d_in[6];
    const float* lnf_b   = (const float*)d_in[7];
    const float* sq_w    = (const float*)d_in[8];
    const float* sq_b    = (const float*)d_in[9];
    const float* full_w  = (const float*)d_in[10];
    const float* full_b  = (const float*)d_in[11];
    const float* unsq_w  = (const float*)d_in[12];
    const float* unsq_b  = (const float*)d_in[13];
    const float* ln2_g   = (const float*)d_in[14];
    const float* ln2_b   = (const float*)d_in[15];
    const float* conv2_w = (const float*)d_in[16];
    const float* conv2_b = (const float*)d_in[17];
    const float* prelu2  = (const float*)d_in[18];
    const float* lnm_g   = (const float*)d_in[19];
    const float* lnm_b   = (const float*)d_in[20];

    float* ws   = (float*)d_ws;
    float* xbuf = ws;
    float* xn   = ws + (size_t)kNX;
    float* bufA = ws + 2 * (size_t)kNX;          // kNM: ln-out / xin / dbl
    float* bufB = bufA + (size_t)kNM;            // kNM: s1 / z
    float* bufC = bufB + (size_t)kNM;            // kNM: s2 / xc / ymid
    float* wT   = bufC + (size_t)kNM;
    float* in_wT[2]  = { wT, wT + 2 * kD * kH };
    float* xp_wT[2]  = { wT + 2 * (2 * kD * kH), wT + 2 * (2 * kD * kH) + kDBL * kD };
    float* out_wT[2] = { wT + 2 * (2 * kD * kH) + 2 * kDBL * kD,
                         wT + 2 * (2 * kD * kH) + 2 * kDBL * kD + kH * kD };

    // weight transposes for both mamba directions
    for (int dir = 0; dir < 2; dir++) {
        int wi = 21 + dir * 9;
        const float* in_w  = (const float*)d_in[wi + 0];
        const float* xp_w  = (const float*)d_in[wi + 3];
        const float* out_w = (const float*)d_in[wi + 8];
        transpose_kernel<<<(2 * kD * kH + 255) / 256, 256, 0, stream>>>(in_w, in_wT[dir], 2 * kD, kH);
        transpose_kernel<<<(kDBL * kD + 255) / 256, 256, 0, stream>>>(xp_w, xp_wT[dir], kDBL, kD);
        transpose_kernel<<<(kH * kD + 255) / 256, 256, 0, stream>>>(out_w, out_wT[dir], kH, kD);
    }

    int lnGrid = (kROWS + 3) / 4;
    int nxGrid = (kNX + 255) / 256;
    int nmGrid = (kNM + 255) / 256;

    // stage 1: x = x + fconv(x)
    ln_kernel<<<lnGrid, 256, 0, stream>>>(x, bufA, ln1_g, ln1_b, kROWS);
    fconv_kernel<<<nxGrid, 256, 0, stream>>>(bufA, x, xbuf, conv1_w, conv1_b, prelu1);

    // stage 2: x = x + full(x)
    ln_kernel<<<lnGrid, 256, 0, stream>>>(xbuf, bufA, lnf_g, lnf_b, kROWS);
    squeeze_kernel<<<dim3(kB * kT, (kF + 63) / 64), 64, 0, stream>>>(bufA, bufB, sq_w, sq_b);
    fullmat_kernel<<<dim3(kB * kT, kS), 256, 0, stream>>>(bufB, bufC, full_w, full_b);
    unsqueeze_kernel<<<nxGrid, 256, 0, stream>>>(bufC, xbuf, unsq_w, unsq_b);

    // stage 3: x = x + fconv(x)
    ln_kernel<<<lnGrid, 256, 0, stream>>>(xbuf, bufA, ln2_g, ln2_b, kROWS);
    fconv_kernel<<<nxGrid, 256, 0, stream>>>(bufA, xbuf, xbuf, conv2_w, conv2_b, prelu2);

    // mamba input: xn = LN(x)
    ln_kernel<<<lnGrid, 256, 0, stream>>>(xbuf, xn, lnm_g, lnm_b, kROWS);

    for (int dir = 0; dir < 2; dir++) {
        int wi = 21 + dir * 9;
        const float* conv_w = (const float*)d_in[wi + 1];
        const float* conv_b = (const float*)d_in[wi + 2];
        const float* dt_w   = (const float*)d_in[wi + 4];
        const float* dt_b   = (const float*)d_in[wi + 5];
        const float* A_log  = (const float*)d_in[wi + 6];
        const float* Dp     = (const float*)d_in[wi + 7];

        inproj_kernel<<<kROWS / 8, 384, 0, stream>>>(xn, in_wT[dir], bufA, bufB, dir);
        mconv_kernel<<<nmGrid, 256, 0, stream>>>(bufA, bufC, conv_w, conv_b);
        xpproj_kernel<<<kROWS / 4, 256, 0, stream>>>(bufC, bufA, xp_wT[dir]);
        scan_kernel<<<kBM, kD, 0, stream>>>(bufA, bufB, bufC, A_log, dt_w, dt_b, Dp);
        outproj_kernel<<<kROWS / 8, 128, 0, stream>>>(bufC, out_wT[dir], xbuf, (float*)d_out, dir);
    }
}

// Round 3
// 1595.515 us; speedup vs baseline: 1.0287x; 1.0287x over previous
//
#include <hip/hip_runtime.h>
#include <math.h>

// Problem constants
constexpr int kB   = 2;
constexpr int kF   = 257;   // FQ
constexpr int kT   = 100;
constexpr int kH   = 96;
constexpr int kS   = 8;
constexpr int kD   = 192;   // DIN
constexpr int kN   = 16;
constexpr int kR   = 6;
constexpr int kKF  = 5;
constexpr int kKM  = 4;
constexpr int kG   = 8;     // GROUPS
constexpr int kGC  = kH / kG;        // 12
constexpr int kBM  = kB * kF;        // 514
constexpr int kROWS = kB * kF * kT;  // 51400
constexpr int kNX  = kROWS * kH;     // 4,934,400
constexpr int kNM  = kROWS * kD;     // 9,868,800
constexpr int kDBL = kR + 2 * kN;    // 38

__device__ inline float wave_reduce_sum(float v) {
    for (int o = 32; o > 0; o >>= 1) v += __shfl_xor(v, o, 64);
    return v;
}
__device__ inline float silu_f(float x) { return x / (1.f + __expf(-x)); }
__device__ inline float softplus_f(float x) { return x > 20.f ? x : log1pf(__expf(x)); }

// ---------------- LayerNorm over H=96, one wave per row ----------------
__global__ void ln_kernel(const float* __restrict__ in, float* __restrict__ out,
                          const float* __restrict__ g, const float* __restrict__ b,
                          int rows) {
    int wave = threadIdx.x >> 6;
    int lane = threadIdx.x & 63;
    int r = blockIdx.x * 4 + wave;
    if (r >= rows) return;
    const float* p = in + (size_t)r * kH;
    float v0 = p[lane];
    float v1 = (lane < 32) ? p[64 + lane] : 0.f;
    float s = wave_reduce_sum(v0 + v1);
    float mean = s * (1.f / 96.f);
    float d0 = v0 - mean;
    float d1 = (lane < 32) ? (v1 - mean) : 0.f;
    float vs = wave_reduce_sum(d0 * d0 + d1 * d1);
    float rstd = rsqrtf(vs * (1.f / 96.f) + 1e-5f);
    float* q = out + (size_t)r * kH;
    q[lane] = d0 * rstd * g[lane] + b[lane];
    if (lane < 32) q[64 + lane] = d1 * rstd * g[64 + lane] + b[64 + lane];
}

// ---------------- freq-conv stage v2 ----------------
// block = (g, t, b); LDS strip [261][12] over F (2-col zero pad each side);
// lane = (hh = l%12, fi = l/12); slot = wave*5+fi owns f in [slot*13, slot*13+13);
// sliding 5-column register window, 60 weights in registers per lane.
// Lanes with fi==5 (60..63) would DUPLICATE another wave's slot -> in-place
// stage-3 call (resid==out) races -> they must retire after staging.
#define FDOT(S,K) \
  acc += xw[S][0].x*wr[K][0] + xw[S][0].y*wr[K][1] + xw[S][0].z*wr[K][2] + xw[S][0].w*wr[K][3] \
       + xw[S][1].x*wr[K][4] + xw[S][1].y*wr[K][5] + xw[S][1].z*wr[K][6] + xw[S][1].w*wr[K][7] \
       + xw[S][2].x*wr[K][8] + xw[S][2].y*wr[K][9] + xw[S][2].z*wr[K][10]+ xw[S][2].w*wr[K][11];

#define FSTEP(S0,S1,S2,S3,S4)                                              \
  if (f < fmax) {                                                          \
    const float4* cp = (const float4*)(Xs + (f + 4) * 12);                 \
    xw[S4][0] = cp[0]; xw[S4][1] = cp[1]; xw[S4][2] = cp[2];               \
    float acc = bias;                                                      \
    FDOT(S0,0) FDOT(S1,1) FDOT(S2,2) FDOT(S3,3) FDOT(S4,4)                 \
    float yv = acc > 0.f ? acc : alpha_h * acc;                            \
    size_t oi = ((size_t)(bb * kF + f) * kT + tt) * kH + g12 + hh;         \
    out[oi] = resid[oi] + yv;                                              \
    f++;                                                                   \
  }

__global__ __launch_bounds__(256)
void fconv_kernel(const float* __restrict__ ln, const float* __restrict__ resid,
                  float* __restrict__ out, const float* __restrict__ w,
                  const float* __restrict__ cb, const float* __restrict__ alpha) {
    __shared__ float Xs[261 * 12];
    __shared__ float Ws[kGC * kKF * 12];  // 720
    int g = blockIdx.x, tt = blockIdx.y, bb = blockIdx.z;
    int g12 = g * 12;
    int tid = threadIdx.x;

    for (int i = tid; i < 720; i += 256) Ws[i] = w[g * 720 + i];
    for (int i = tid; i < 257 * 12; i += 256) {
        int fs = i / 12, ci = i - fs * 12;
        Xs[(fs + 2) * 12 + ci] = ln[((size_t)(bb * kF + fs) * kT + tt) * kH + g12 + ci];
    }
    if (tid < 48) {
        const int padr[4] = {0, 1, 259, 260};
        Xs[padr[tid / 12] * 12 + (tid % 12)] = 0.f;
    }
    __syncthreads();

    int lane = tid & 63, wave = tid >> 6;
    int hh = lane % 12, fi = lane / 12;
    if (fi >= 5) return;                      // would duplicate slot wave*5+5 -> race when resid==out
    int slot = wave * 5 + fi;
    int f0 = slot * 13;
    int fmax = min(f0 + 13, kF);

    float wr[5][12];
    #pragma unroll
    for (int k = 0; k < 5; k++)
        #pragma unroll
        for (int ci = 0; ci < 12; ci++)
            wr[k][ci] = Ws[hh * 60 + ci * 5 + k];

    float bias = cb[g12 + hh];
    float alpha_h = alpha[g12 + hh];

    float4 xw[5][3];
    #pragma unroll
    for (int s = 0; s < 4; s++) {
        int row = min(f0 + s, 260);
        const float4* cp = (const float4*)(Xs + row * 12);
        xw[s][0] = cp[0]; xw[s][1] = cp[1]; xw[s][2] = cp[2];
    }
    int f = f0;
    for (int rep = 0; rep < 3; rep++) {
        FSTEP(0,1,2,3,4)
        FSTEP(1,2,3,4,0)
        FSTEP(2,3,4,0,1)
        FSTEP(3,4,0,1,2)
        FSTEP(4,0,1,2,3)
    }
}

// ---------------- full stage: squeeze H->S with SiLU ----------------
__global__ void squeeze_kernel(const float* __restrict__ ln, float* __restrict__ s1,
                               const float* __restrict__ sqw, const float* __restrict__ sqb) {
    int bt = blockIdx.x;                       // b*kT + t
    int f = blockIdx.y * 64 + threadIdx.x;
    if (f >= kF) return;
    int b = bt / kT, t = bt % kT;
    const float* row = ln + ((size_t)(b * kF + f) * kT + t) * kH;
    float acc[kS];
    for (int s = 0; s < kS; s++) acc[s] = 0.f;
    for (int h = 0; h < kH; h++) {
        float v = row[h];
        for (int s = 0; s < kS; s++) acc[s] += v * sqw[s * kH + h];
    }
    for (int s = 0; s < kS; s++)
        s1[((size_t)bt * kS + s) * kF + f] = silu_f(acc[s] + sqb[s]);
}

// ---------------- full stage: per-group 257x257 matmul over F ----------------
__global__ void fullmat_kernel(const float* __restrict__ s1, float* __restrict__ s2,
                               const float* __restrict__ fw, const float* __restrict__ fb) {
    int bt = blockIdx.x, g = blockIdx.y;
    const float* srow = s1 + ((size_t)bt * kS + g) * kF;
    for (int k = threadIdx.x; k < kF; k += blockDim.x) {
        const float* wrow = fw + ((size_t)g * kF + k) * kF;
        float acc = fb[g * kF + k];
        for (int ff = 0; ff < kF; ff++) acc += srow[ff] * wrow[ff];
        s2[((size_t)bt * kS + g) * kF + k] = acc;
    }
}

// ---------------- full stage: unsqueeze S->H + SiLU + residual ----------------
__global__ void unsqueeze_kernel(const float* __restrict__ s2, float* __restrict__ x,
                                 const float* __restrict__ uw, const float* __restrict__ ub) {
    int idx = blockIdx.x * blockDim.x + threadIdx.x;
    if (idx >= kNX) return;
    int h = idx % kH;
    int t = (idx / kH) % kT;
    int f = (idx / (kH * kT)) % kF;
    int b = idx / (kH * kT * kF);
    int bt = b * kT + t;
    float acc = ub[h];
    for (int s = 0; s < kS; s++)
        acc += s2[((size_t)bt * kS + s) * kF + f] * uw[h * kS + s];
    x[idx] += silu_f(acc);
}

// ---------------- small weight transpose ----------------
__global__ void transpose_kernel(const float* __restrict__ in, float* __restrict__ out,
                                 int rows, int cols) {
    int idx = blockIdx.x * blockDim.x + threadIdx.x;
    if (idx >= rows * cols) return;
    int r = idx / cols, c = idx % cols;
    out[c * rows + r] = in[idx];
}

// out_w [96][192] -> padded transpose wp [192][128] (cols >=96 zero)
__global__ void outpad_kernel(const float* __restrict__ w, float* __restrict__ wp) {
    int i = blockIdx.x * 256 + threadIdx.x;
    if (i >= kD * 128) return;
    int d = i >> 7, h = i & 127;
    wp[i] = (h < kH) ? w[h * kD + d] : 0.f;
}

// ---------------- mamba in-proj GEMM: [51400x96] @ [96x384] ----------------
__global__ __launch_bounds__(128)
void inproj_gemm(const float* __restrict__ xn, const float* __restrict__ wT,
                 float* __restrict__ xin, float* __restrict__ z) {
    __shared__ float Al[96 * 64];
    int r0 = blockIdx.x * 64;
    int c0 = blockIdx.y * 128;
    int tid = threadIdx.x;
    for (int i = tid; i < 96 * 64; i += 128) {
        int m = i & 63, h = i >> 6;
        int r = r0 + m; if (r >= kROWS) r = kROWS - 1;
        Al[h * 64 + m] = xn[(size_t)r * kH + h];
    }
    __syncthreads();
    int rt = tid >> 4, ct = tid & 15;
    const float* bp = wT + c0 + ct * 8;
    float4 acc[8][2];
    #pragma unroll
    for (int i = 0; i < 8; i++) {
        acc[i][0] = make_float4(0.f, 0.f, 0.f, 0.f);
        acc[i][1] = make_float4(0.f, 0.f, 0.f, 0.f);
    }
    for (int h = 0; h < 96; h++) {
        float4 a0 = *(const float4*)&Al[h * 64 + rt * 8];
        float4 a1 = *(const float4*)&Al[h * 64 + rt * 8 + 4];
        float4 b0 = *(const float4*)&bp[(size_t)h * 384];
        float4 b1 = *(const float4*)&bp[(size_t)h * 384 + 4];
        float ar[8] = {a0.x, a0.y, a0.z, a0.w, a1.x, a1.y, a1.z, a1.w};
        #pragma unroll
        for (int i = 0; i < 8; i++) {
            float av = ar[i];
            acc[i][0].x += av * b0.x; acc[i][0].y += av * b0.y;
            acc[i][0].z += av * b0.z; acc[i][0].w += av * b0.w;
            acc[i][1].x += av * b1.x; acc[i][1].y += av * b1.y;
            acc[i][1].z += av * b1.z; acc[i][1].w += av * b1.w;
        }
    }
    int cbase = c0 + ct * 8;
    #pragma unroll
    for (int i = 0; i < 8; i++) {
        int r = r0 + rt * 8 + i;
        if (r >= kROWS) break;
        if (cbase < kD) {
            *(float4*)&xin[(size_t)r * kD + cbase]     = acc[i][0];
            *(float4*)&xin[(size_t)r * kD + cbase + 4] = acc[i][1];
        } else {
            *(float4*)&z[(size_t)r * kD + cbase - kD]     = acc[i][0];
            *(float4*)&z[(size_t)r * kD + cbase - kD + 4] = acc[i][1];
        }
    }
}

// ---------------- mamba out-proj GEMM + combine: [51400x192] @ [192x128pad] ----------------
__global__ __launch_bounds__(128)
void outproj_gemm(const float* __restrict__ ym, const float* __restrict__ wp,
                  const float* __restrict__ xres, float* __restrict__ out, int dir) {
    __shared__ float Al[192 * 64];  // 48 KiB
    int r0 = blockIdx.x * 64;
    int tid = threadIdx.x;
    for (int i = tid; i < 192 * 64; i += 128) {
        int m = i & 63, h = i >> 6;
        int r = r0 + m; if (r >= kROWS) r = kROWS - 1;
        Al[h * 64 + m] = ym[(size_t)r * kD + h];
    }
    __syncthreads();
    int rt = tid >> 4, ct = tid & 15;
    const float* bp = wp + ct * 8;
    float4 acc[8][2];
    #pragma unroll
    for (int i = 0; i < 8; i++) {
        acc[i][0] = make_float4(0.f, 0.f, 0.f, 0.f);
        acc[i][1] = make_float4(0.f, 0.f, 0.f, 0.f);
    }
    for (int h = 0; h < 192; h++) {
        float4 a0 = *(const float4*)&Al[h * 64 + rt * 8];
        float4 a1 = *(const float4*)&Al[h * 64 + rt * 8 + 4];
        float4 b0 = *(const float4*)&bp[h * 128];
        float4 b1 = *(const float4*)&bp[h * 128 + 4];
        float ar[8] = {a0.x, a0.y, a0.z, a0.w, a1.x, a1.y, a1.z, a1.w};
        #pragma unroll
        for (int i = 0; i < 8; i++) {
            float av = ar[i];
            acc[i][0].x += av * b0.x; acc[i][0].y += av * b0.y;
            acc[i][0].z += av * b0.z; acc[i][0].w += av * b0.w;
            acc[i][1].x += av * b1.x; acc[i][1].y += av * b1.y;
            acc[i][1].z += av * b1.z; acc[i][1].w += av * b1.w;
        }
    }
    int cbase = ct * 8;
    if (cbase >= kH) return;
    #pragma unroll
    for (int i = 0; i < 8; i++) {
        int r = r0 + rt * 8 + i;
        if (r >= kROWS) break;
        float4 v0 = acc[i][0], v1 = acc[i][1];
        size_t o = (size_t)r * kH + cbase;
        if (dir == 0) {
            float4 x0 = *(const float4*)&xres[o], x1 = *(const float4*)&xres[o + 4];
            v0.x = x0.x + 0.5f * v0.x; v0.y = x0.y + 0.5f * v0.y;
            v0.z = x0.z + 0.5f * v0.z; v0.w = x0.w + 0.5f * v0.w;
            v1.x = x1.x + 0.5f * v1.x; v1.y = x1.y + 0.5f * v1.y;
            v1.z = x1.z + 0.5f * v1.z; v1.w = x1.w + 0.5f * v1.w;
        } else {
            float4 x0 = *(const float4*)&out[o], x1 = *(const float4*)&out[o + 4];
            v0.x = x0.x + 0.5f * v0.x; v0.y = x0.y + 0.5f * v0.y;
            v0.z = x0.z + 0.5f * v0.z; v0.w = x0.w + 0.5f * v0.w;
            v1.x = x1.x + 0.5f * v1.x; v1.y = x1.y + 0.5f * v1.y;
            v1.z = x1.z + 0.5f * v1.z; v1.w = x1.w + 0.5f * v1.w;
        }
        *(float4*)&out[o] = v0;
        *(float4*)&out[o + 4] = v1;
    }
}

// ---------------- mamba depthwise conv over T + SiLU (dir: 0 causal, 1 anti-causal) ----------------
__global__ void mconv_kernel(const float* __restrict__ xin, float* __restrict__ xc,
                             const float* __restrict__ cw, const float* __restrict__ cb, int dir) {
    int qid = blockIdx.x * blockDim.x + threadIdx.x;
    if (qid >= kROWS * 48) return;
    int r = qid / 48, d4 = (qid - r * 48) * 4;
    int bm = r / kT, t = r - bm * kT;
    float4 acc = make_float4(cb[d4], cb[d4 + 1], cb[d4 + 2], cb[d4 + 3]);
    #pragma unroll
    for (int k = 0; k < kKM; k++) {
        int ts = dir ? (t + 3 - k) : (t + k - 3);
        if (ts < 0 || ts >= kT) continue;
        float4 v = *(const float4*)&xin[((size_t)bm * kT + ts) * kD + d4];
        acc.x += v.x * cw[(d4 + 0) * kKM + k];
        acc.y += v.y * cw[(d4 + 1) * kKM + k];
        acc.z += v.z * cw[(d4 + 2) * kKM + k];
        acc.w += v.w * cw[(d4 + 3) * kKM + k];
    }
    float4 o = make_float4(silu_f(acc.x), silu_f(acc.y), silu_f(acc.z), silu_f(acc.w));
    *(float4*)&xc[(size_t)r * kD + d4] = o;
}

// ---------------- mamba x-proj: dbl = xc @ xp_w.T (38 outs), one wave per row ----------------
__global__ void xpproj_kernel(const float* __restrict__ xc, float* __restrict__ dbl,
                              const float* __restrict__ xpw) {
    int wave = threadIdx.x >> 6, lane = threadIdx.x & 63;
    int r = blockIdx.x * 4 + wave;
    if (r >= kROWS || lane >= kDBL) return;
    const float4* rowq = (const float4*)(xc + (size_t)r * kD);
    const float4* wq = (const float4*)(xpw + (size_t)lane * kD);
    float acc = 0.f;
    #pragma unroll 8
    for (int q = 0; q < kD / 4; q++) {
        float4 a = rowq[q], w = wq[q];
        acc += a.x * w.x + a.y * w.y + a.z * w.z + a.w * w.w;
    }
    dbl[(size_t)r * kDBL + lane] = acc;
}

// ---------------- mamba selective scan (dir: 0 fwd, 1 bwd over t) ----------------
__global__ void scan_kernel(const float* __restrict__ dbl, const float* __restrict__ z,
                            float* __restrict__ xcy,
                            const float* __restrict__ A_log, const float* __restrict__ dtw,
                            const float* __restrict__ dtb, const float* __restrict__ Dp, int dir) {
    int bm = blockIdx.x;
    int d = threadIdx.x;
    float A[kN], hst[kN], dw[kR];
    for (int n = 0; n < kN; n++) { A[n] = -__expf(A_log[d * kN + n]); hst[n] = 0.f; }
    for (int r = 0; r < kR; r++) dw[r] = dtw[d * kR + r];
    float db = dtb[d], Dv = Dp[d];
    for (int i = 0; i < kT; i++) {
        int t = dir ? (kT - 1 - i) : i;
        size_t rb = (size_t)(bm * kT + t);
        const float* dr = dbl + rb * kDBL;
        float s = db;
        #pragma unroll
        for (int r = 0; r < kR; r++) s += dr[r] * dw[r];
        float dt = softplus_f(s);
        float xv = xcy[rb * kD + d];
        float dtx = dt * xv;
        float y = 0.f;
        #pragma unroll
        for (int n = 0; n < kN; n++) {
            hst[n] = __expf(dt * A[n]) * hst[n] + dtx * dr[kR + n];
            y += hst[n] * dr[kR + kN + n];
        }
        float zv = z[rb * kD + d];
        xcy[rb * kD + d] = (y + xv * Dv) * silu_f(zv);
    }
}

extern "C" void kernel_launch(void* const* d_in, const int* in_sizes, int n_in,
                              void* d_out, int out_size, void* d_ws, size_t ws_size,
                              hipStream_t stream) {
    const float* x       = (const float*)d_in[0];
    const float* ln1_g   = (const float*)d_in[1];
    const float* ln1_b   = (const float*)d_in[2];
    const float* conv1_w = (const float*)d_in[3];
    const float* conv1_b = (const float*)d_in[4];
    const float* prelu1  = (const float*)d_in[5];
    const float* lnf_g   = (const float*)d_in[6];
    const float* lnf_b   = (const float*)d_in[7];
    const float* sq_w    = (const float*)d_in[8];
    const float* sq_b    = (const float*)d_in[9];
    const float* full_w  = (const float*)d_in[10];
    const float* full_b  = (const float*)d_in[11];
    const float* unsq_w  = (const float*)d_in[12];
    const float* unsq_b  = (const float*)d_in[13];
    const float* ln2_g   = (const float*)d_in[14];
    const float* ln2_b   = (const float*)d_in[15];
    const float* conv2_w = (const float*)d_in[16];
    const float* conv2_b = (const float*)d_in[17];
    const float* prelu2  = (const float*)d_in[18];
    const float* lnm_g   = (const float*)d_in[19];
    const float* lnm_b   = (const float*)d_in[20];

    float* ws   = (float*)d_ws;
    float* xbuf = ws;
    float* xn   = ws + (size_t)kNX;
    float* bufA = ws + 2 * (size_t)kNX;          // kNM: ln-out / xin / dbl
    float* bufB = bufA + (size_t)kNM;            // kNM: s1 / z
    float* bufC = bufB + (size_t)kNM;            // kNM: s2 / xc / ymid
    float* wTs  = bufC + (size_t)kNM;
    float* in_wT[2]  = { wTs, wTs + 2 * kD * kH };                  // [96][384] each
    float* out_wp[2] = { wTs + 2 * (2 * kD * kH),
                         wTs + 2 * (2 * kD * kH) + kD * 128 };      // [192][128] each

    for (int dir = 0; dir < 2; dir++) {
        int wi = 21 + dir * 9;
        const float* in_w  = (const float*)d_in[wi + 0];
        const float* out_w = (const float*)d_in[wi + 8];
        transpose_kernel<<<(2 * kD * kH + 255) / 256, 256, 0, stream>>>(in_w, in_wT[dir], 2 * kD, kH);
        outpad_kernel<<<(kD * 128 + 255) / 256, 256, 0, stream>>>(out_w, out_wp[dir]);
    }

    int lnGrid = (kROWS + 3) / 4;
    int nxGrid = (kNX + 255) / 256;
    dim3 fcGrid(kG, kT, kB);

    // stage 1: x = x + fconv(x)
    ln_kernel<<<lnGrid, 256, 0, stream>>>(x, bufA, ln1_g, ln1_b, kROWS);
    fconv_kernel<<<fcGrid, 256, 0, stream>>>(bufA, x, xbuf, conv1_w, conv1_b, prelu1);

    // stage 2: x = x + full(x)
    ln_kernel<<<lnGrid, 256, 0, stream>>>(xbuf, bufA, lnf_g, lnf_b, kROWS);
    squeeze_kernel<<<dim3(kB * kT, (kF + 63) / 64), 64, 0, stream>>>(bufA, bufB, sq_w, sq_b);
    fullmat_kernel<<<dim3(kB * kT, kS), 256, 0, stream>>>(bufB, bufC, full_w, full_b);
    unsqueeze_kernel<<<nxGrid, 256, 0, stream>>>(bufC, xbuf, unsq_w, unsq_b);

    // stage 3: x = x + fconv(x)  (in-place: resid == out)
    ln_kernel<<<lnGrid, 256, 0, stream>>>(xbuf, bufA, ln2_g, ln2_b, kROWS);
    fconv_kernel<<<fcGrid, 256, 0, stream>>>(bufA, xbuf, xbuf, conv2_w, conv2_b, prelu2);

    // mamba input: xn = LN(x)
    ln_kernel<<<lnGrid, 256, 0, stream>>>(xbuf, xn, lnm_g, lnm_b, kROWS);

    for (int dir = 0; dir < 2; dir++) {
        int wi = 21 + dir * 9;
        const float* conv_w = (const float*)d_in[wi + 1];
        const float* conv_b = (const float*)d_in[wi + 2];
        const float* xp_w   = (const float*)d_in[wi + 3];
        const float* dt_w   = (const float*)d_in[wi + 4];
        const float* dt_b   = (const float*)d_in[wi + 5];
        const float* A_log  = (const float*)d_in[wi + 6];
        const float* Dp     = (const float*)d_in[wi + 7];

        inproj_gemm<<<dim3((kROWS + 63) / 64, 3), 128, 0, stream>>>(xn, in_wT[dir], bufA, bufB);
        mconv_kernel<<<(kROWS * 48 + 255) / 256, 256, 0, stream>>>(bufA, bufC, conv_w, conv_b, dir);
        xpproj_kernel<<<(kROWS + 3) / 4, 256, 0, stream>>>(bufC, bufA, xp_w);
        scan_kernel<<<kBM, kD, 0, stream>>>(bufA, bufB, bufC, A_log, dt_w, dt_b, Dp, dir);
        outproj_gemm<<<(kROWS + 63) / 64, 128, 0, stream>>>(bufC, out_wp[dir], xbuf, (float*)d_out, dir);
    }
}

// Round 4
// 1128.271 us; speedup vs baseline: 1.4546x; 1.4141x over previous
//
#include <hip/hip_runtime.h>
#include <math.h>

// Problem constants
constexpr int kB   = 2;
constexpr int kF   = 257;   // FQ
constexpr int kT   = 100;
constexpr int kH   = 96;
constexpr int kS   = 8;
constexpr int kD   = 192;   // DIN
constexpr int kN   = 16;
constexpr int kR   = 6;
constexpr int kKF  = 5;
constexpr int kKM  = 4;
constexpr int kG   = 8;     // GROUPS
constexpr int kGC  = kH / kG;        // 12
constexpr int kBM  = kB * kF;        // 514
constexpr int kROWS = kB * kF * kT;  // 51400
constexpr int kNX  = kROWS * kH;     // 4,934,400
constexpr int kNM  = kROWS * kD;     // 9,868,800
constexpr int kDBL = kR + 2 * kN;    // 38
constexpr int kDBLP = 48;            // padded

__device__ inline float wave_reduce_sum(float v) {
    for (int o = 32; o > 0; o >>= 1) v += __shfl_xor(v, o, 64);
    return v;
}
__device__ inline float silu_f(float x) { return x / (1.f + __expf(-x)); }
__device__ inline float softplus_f(float x) { return x > 20.f ? x : log1pf(__expf(x)); }

// ---------------- LayerNorm over H=96, one wave per row ----------------
__global__ void ln_kernel(const float* __restrict__ in, float* __restrict__ out,
                          const float* __restrict__ g, const float* __restrict__ b,
                          int rows) {
    int wave = threadIdx.x >> 6;
    int lane = threadIdx.x & 63;
    int r = blockIdx.x * 4 + wave;
    if (r >= rows) return;
    const float* p = in + (size_t)r * kH;
    float v0 = p[lane];
    float v1 = (lane < 32) ? p[64 + lane] : 0.f;
    float s = wave_reduce_sum(v0 + v1);
    float mean = s * (1.f / 96.f);
    float d0 = v0 - mean;
    float d1 = (lane < 32) ? (v1 - mean) : 0.f;
    float vs = wave_reduce_sum(d0 * d0 + d1 * d1);
    float rstd = rsqrtf(vs * (1.f / 96.f) + 1e-5f);
    float* q = out + (size_t)r * kH;
    q[lane] = d0 * rstd * g[lane] + b[lane];
    if (lane < 32) q[64 + lane] = d1 * rstd * g[64 + lane] + b[64 + lane];
}

// ---------------- freq-conv stage ----------------
#define FDOT(S,K) \
  acc += xw[S][0].x*wr[K][0] + xw[S][0].y*wr[K][1] + xw[S][0].z*wr[K][2] + xw[S][0].w*wr[K][3] \
       + xw[S][1].x*wr[K][4] + xw[S][1].y*wr[K][5] + xw[S][1].z*wr[K][6] + xw[S][1].w*wr[K][7] \
       + xw[S][2].x*wr[K][8] + xw[S][2].y*wr[K][9] + xw[S][2].z*wr[K][10]+ xw[S][2].w*wr[K][11];

#define FSTEP(S0,S1,S2,S3,S4)                                              \
  if (f < fmax) {                                                          \
    const float4* cp = (const float4*)(Xs + (f + 4) * 12);                 \
    xw[S4][0] = cp[0]; xw[S4][1] = cp[1]; xw[S4][2] = cp[2];               \
    float acc = bias;                                                      \
    FDOT(S0,0) FDOT(S1,1) FDOT(S2,2) FDOT(S3,3) FDOT(S4,4)                 \
    float yv = acc > 0.f ? acc : alpha_h * acc;                            \
    size_t oi = ((size_t)(bb * kF + f) * kT + tt) * kH + g12 + hh;         \
    out[oi] = resid[oi] + yv;                                              \
    f++;                                                                   \
  }

__global__ __launch_bounds__(256)
void fconv_kernel(const float* __restrict__ ln, const float* __restrict__ resid,
                  float* __restrict__ out, const float* __restrict__ w,
                  const float* __restrict__ cb, const float* __restrict__ alpha) {
    __shared__ float Xs[261 * 12];
    __shared__ float Ws[kGC * kKF * 12];  // 720
    int g = blockIdx.x, tt = blockIdx.y, bb = blockIdx.z;
    int g12 = g * 12;
    int tid = threadIdx.x;

    for (int i = tid; i < 720; i += 256) Ws[i] = w[g * 720 + i];
    for (int i = tid; i < 257 * 12; i += 256) {
        int fs = i / 12, ci = i - fs * 12;
        Xs[(fs + 2) * 12 + ci] = ln[((size_t)(bb * kF + fs) * kT + tt) * kH + g12 + ci];
    }
    if (tid < 48) {
        const int padr[4] = {0, 1, 259, 260};
        Xs[padr[tid / 12] * 12 + (tid % 12)] = 0.f;
    }
    __syncthreads();

    int lane = tid & 63, wave = tid >> 6;
    int hh = lane % 12, fi = lane / 12;
    if (fi >= 5) return;                      // duplicate-slot lanes must retire (in-place race)
    int slot = wave * 5 + fi;
    int f0 = slot * 13;
    int fmax = min(f0 + 13, kF);

    float wr[5][12];
    #pragma unroll
    for (int k = 0; k < 5; k++)
        #pragma unroll
        for (int ci = 0; ci < 12; ci++)
            wr[k][ci] = Ws[hh * 60 + ci * 5 + k];

    float bias = cb[g12 + hh];
    float alpha_h = alpha[g12 + hh];

    float4 xw[5][3];
    #pragma unroll
    for (int s = 0; s < 4; s++) {
        int row = min(f0 + s, 260);
        const float4* cp = (const float4*)(Xs + row * 12);
        xw[s][0] = cp[0]; xw[s][1] = cp[1]; xw[s][2] = cp[2];
    }
    int f = f0;
    for (int rep = 0; rep < 3; rep++) {
        FSTEP(0,1,2,3,4)
        FSTEP(1,2,3,4,0)
        FSTEP(2,3,4,0,1)
        FSTEP(3,4,0,1,2)
        FSTEP(4,0,1,2,3)
    }
}

// ---------------- full stage: squeeze H->S with SiLU ----------------
__global__ void squeeze_kernel(const float* __restrict__ ln, float* __restrict__ s1,
                               const float* __restrict__ sqw, const float* __restrict__ sqb) {
    int bt = blockIdx.x;                       // b*kT + t
    int f = blockIdx.y * 64 + threadIdx.x;
    if (f >= kF) return;
    int b = bt / kT, t = bt % kT;
    const float* row = ln + ((size_t)(b * kF + f) * kT + t) * kH;
    float acc[kS];
    for (int s = 0; s < kS; s++) acc[s] = 0.f;
    for (int h = 0; h < kH; h++) {
        float v = row[h];
        for (int s = 0; s < kS; s++) acc[s] += v * sqw[s * kH + h];
    }
    for (int s = 0; s < kS; s++)
        s1[((size_t)bt * kS + s) * kF + f] = silu_f(acc[s] + sqb[s]);
}

// ---------------- full stage: per-group GEMM over F ----------------
// C[bt][k] = sum_f s1[bt][g][f] * fw[g][k][f] + fb[g][k]
// blocks: (ktile x5, bttile x4, g x8); 256 thr; thread 4x4; f-chunks of 64.
__global__ __launch_bounds__(256)
void fullmat_gemm(const float* __restrict__ s1, float* __restrict__ s2,
                  const float* __restrict__ fw, const float* __restrict__ fb) {
    __shared__ float As[64 * 64];  // [fk][bt]
    __shared__ float Bs[64 * 64];  // [fk][k]
    int k0 = blockIdx.x * 64, bt0 = blockIdx.y * 64, g = blockIdx.z;
    int tid = threadIdx.x;
    int rt = tid >> 4, ct = tid & 15;
    float acc[4][4];
    #pragma unroll
    for (int i = 0; i < 4; i++)
        #pragma unroll
        for (int j = 0; j < 4; j++) acc[i][j] = 0.f;

    for (int f0 = 0; f0 < kF; f0 += 64) {
        int fcnt = min(64, kF - f0);
        for (int i = tid; i < 64 * 64; i += 256) {
            int m = i & 63, fk = i >> 6;
            int bt = bt0 + m, f = f0 + fk;
            As[fk * 64 + m] = (bt < kB * kT && f < kF)
                ? s1[((size_t)bt * kS + g) * kF + f] : 0.f;
            int k = k0 + m;
            Bs[fk * 64 + m] = (k < kF && f < kF)
                ? fw[(size_t)g * kF * kF + (size_t)k * kF + f] : 0.f;
        }
        __syncthreads();
        for (int f = 0; f < fcnt; f++) {
            float4 a4 = *(const float4*)&As[f * 64 + rt * 4];
            float4 b4 = *(const float4*)&Bs[f * 64 + ct * 4];
            float ar[4] = {a4.x, a4.y, a4.z, a4.w};
            float br[4] = {b4.x, b4.y, b4.z, b4.w};
            #pragma unroll
            for (int i = 0; i < 4; i++)
                #pragma unroll
                for (int j = 0; j < 4; j++) acc[i][j] += ar[i] * br[j];
        }
        __syncthreads();
    }
    #pragma unroll
    for (int i = 0; i < 4; i++) {
        int bt = bt0 + rt * 4 + i;
        if (bt >= kB * kT) continue;
        #pragma unroll
        for (int j = 0; j < 4; j++) {
            int k = k0 + ct * 4 + j;
            if (k >= kF) continue;
            s2[((size_t)bt * kS + g) * kF + k] = acc[i][j] + fb[g * kF + k];
        }
    }
}

// ---------------- full stage: unsqueeze S->H + SiLU + residual ----------------
__global__ void unsqueeze_kernel(const float* __restrict__ s2, float* __restrict__ x,
                                 const float* __restrict__ uw, const float* __restrict__ ub) {
    int idx = blockIdx.x * blockDim.x + threadIdx.x;
    if (idx >= kNX) return;
    int h = idx % kH;
    int t = (idx / kH) % kT;
    int f = (idx / (kH * kT)) % kF;
    int b = idx / (kH * kT * kF);
    int bt = b * kT + t;
    float acc = ub[h];
    for (int s = 0; s < kS; s++)
        acc += s2[((size_t)bt * kS + s) * kF + f] * uw[h * kS + s];
    x[idx] += silu_f(acc);
}

// ---------------- small weight transpose ----------------
__global__ void transpose_kernel(const float* __restrict__ in, float* __restrict__ out,
                                 int rows, int cols) {
    int idx = blockIdx.x * blockDim.x + threadIdx.x;
    if (idx >= rows * cols) return;
    int r = idx / cols, c = idx % cols;
    out[c * rows + r] = in[idx];
}

// out_w [96][192] -> padded transpose wp [192][128] (cols >=96 zero)
__global__ void outpad_kernel(const float* __restrict__ w, float* __restrict__ wp) {
    int i = blockIdx.x * 256 + threadIdx.x;
    if (i >= kD * 128) return;
    int d = i >> 7, h = i & 127;
    wp[i] = (h < kH) ? w[h * kD + d] : 0.f;
}

// xp_w [38][192] -> padded transpose wpx [192][48] (cols >=38 zero)
__global__ void xppad_kernel(const float* __restrict__ w, float* __restrict__ wp) {
    int i = blockIdx.x * 256 + threadIdx.x;
    if (i >= kD * kDBLP) return;
    int d = i / kDBLP, n = i % kDBLP;
    wp[i] = (n < kDBL) ? w[n * kD + d] : 0.f;
}

// ---------------- mamba in-proj GEMM: [51400x96] @ [96x384] ----------------
__global__ __launch_bounds__(128)
void inproj_gemm(const float* __restrict__ xn, const float* __restrict__ wT,
                 float* __restrict__ xin, float* __restrict__ z) {
    __shared__ float Al[96 * 64];
    int r0 = blockIdx.x * 64;
    int c0 = blockIdx.y * 128;
    int tid = threadIdx.x;
    for (int i = tid; i < 96 * 64; i += 128) {
        int m = i & 63, h = i >> 6;
        int r = r0 + m; if (r >= kROWS) r = kROWS - 1;
        Al[h * 64 + m] = xn[(size_t)r * kH + h];
    }
    __syncthreads();
    int rt = tid >> 4, ct = tid & 15;
    const float* bp = wT + c0 + ct * 8;
    float4 acc[8][2];
    #pragma unroll
    for (int i = 0; i < 8; i++) {
        acc[i][0] = make_float4(0.f, 0.f, 0.f, 0.f);
        acc[i][1] = make_float4(0.f, 0.f, 0.f, 0.f);
    }
    for (int h = 0; h < 96; h++) {
        float4 a0 = *(const float4*)&Al[h * 64 + rt * 8];
        float4 a1 = *(const float4*)&Al[h * 64 + rt * 8 + 4];
        float4 b0 = *(const float4*)&bp[(size_t)h * 384];
        float4 b1 = *(const float4*)&bp[(size_t)h * 384 + 4];
        float ar[8] = {a0.x, a0.y, a0.z, a0.w, a1.x, a1.y, a1.z, a1.w};
        #pragma unroll
        for (int i = 0; i < 8; i++) {
            float av = ar[i];
            acc[i][0].x += av * b0.x; acc[i][0].y += av * b0.y;
            acc[i][0].z += av * b0.z; acc[i][0].w += av * b0.w;
            acc[i][1].x += av * b1.x; acc[i][1].y += av * b1.y;
            acc[i][1].z += av * b1.z; acc[i][1].w += av * b1.w;
        }
    }
    int cbase = c0 + ct * 8;
    #pragma unroll
    for (int i = 0; i < 8; i++) {
        int r = r0 + rt * 8 + i;
        if (r >= kROWS) break;
        if (cbase < kD) {
            *(float4*)&xin[(size_t)r * kD + cbase]     = acc[i][0];
            *(float4*)&xin[(size_t)r * kD + cbase + 4] = acc[i][1];
        } else {
            *(float4*)&z[(size_t)r * kD + cbase - kD]     = acc[i][0];
            *(float4*)&z[(size_t)r * kD + cbase - kD + 4] = acc[i][1];
        }
    }
}

// ---------------- mamba out-proj GEMM + combine: [51400x192] @ [192x128pad] ----------------
__global__ __launch_bounds__(128)
void outproj_gemm(const float* __restrict__ ym, const float* __restrict__ wp,
                  const float* __restrict__ xres, float* __restrict__ out, int dir) {
    __shared__ float Al[192 * 64];  // 48 KiB
    int r0 = blockIdx.x * 64;
    int tid = threadIdx.x;
    for (int i = tid; i < 192 * 64; i += 128) {
        int m = i & 63, h = i >> 6;
        int r = r0 + m; if (r >= kROWS) r = kROWS - 1;
        Al[h * 64 + m] = ym[(size_t)r * kD + h];
    }
    __syncthreads();
    int rt = tid >> 4, ct = tid & 15;
    const float* bp = wp + ct * 8;
    float4 acc[8][2];
    #pragma unroll
    for (int i = 0; i < 8; i++) {
        acc[i][0] = make_float4(0.f, 0.f, 0.f, 0.f);
        acc[i][1] = make_float4(0.f, 0.f, 0.f, 0.f);
    }
    for (int h = 0; h < 192; h++) {
        float4 a0 = *(const float4*)&Al[h * 64 + rt * 8];
        float4 a1 = *(const float4*)&Al[h * 64 + rt * 8 + 4];
        float4 b0 = *(const float4*)&bp[h * 128];
        float4 b1 = *(const float4*)&bp[h * 128 + 4];
        float ar[8] = {a0.x, a0.y, a0.z, a0.w, a1.x, a1.y, a1.z, a1.w};
        #pragma unroll
        for (int i = 0; i < 8; i++) {
            float av = ar[i];
            acc[i][0].x += av * b0.x; acc[i][0].y += av * b0.y;
            acc[i][0].z += av * b0.z; acc[i][0].w += av * b0.w;
            acc[i][1].x += av * b1.x; acc[i][1].y += av * b1.y;
            acc[i][1].z += av * b1.z; acc[i][1].w += av * b1.w;
        }
    }
    int cbase = ct * 8;
    if (cbase >= kH) return;
    #pragma unroll
    for (int i = 0; i < 8; i++) {
        int r = r0 + rt * 8 + i;
        if (r >= kROWS) break;
        float4 v0 = acc[i][0], v1 = acc[i][1];
        size_t o = (size_t)r * kH + cbase;
        if (dir == 0) {
            float4 x0 = *(const float4*)&xres[o], x1 = *(const float4*)&xres[o + 4];
            v0.x = x0.x + 0.5f * v0.x; v0.y = x0.y + 0.5f * v0.y;
            v0.z = x0.z + 0.5f * v0.z; v0.w = x0.w + 0.5f * v0.w;
            v1.x = x1.x + 0.5f * v1.x; v1.y = x1.y + 0.5f * v1.y;
            v1.z = x1.z + 0.5f * v1.z; v1.w = x1.w + 0.5f * v1.w;
        } else {
            float4 x0 = *(const float4*)&out[o], x1 = *(const float4*)&out[o + 4];
            v0.x = x0.x + 0.5f * v0.x; v0.y = x0.y + 0.5f * v0.y;
            v0.z = x0.z + 0.5f * v0.z; v0.w = x0.w + 0.5f * v0.w;
            v1.x = x1.x + 0.5f * v1.x; v1.y = x1.y + 0.5f * v1.y;
            v1.z = x1.z + 0.5f * v1.z; v1.w = x1.w + 0.5f * v1.w;
        }
        *(float4*)&out[o] = v0;
        *(float4*)&out[o + 4] = v1;
    }
}

// ---------------- mamba depthwise conv over T + SiLU ----------------
__global__ void mconv_kernel(const float* __restrict__ xin, float* __restrict__ xc,
                             const float* __restrict__ cw, const float* __restrict__ cb, int dir) {
    int qid = blockIdx.x * blockDim.x + threadIdx.x;
    if (qid >= kROWS * 48) return;
    int r = qid / 48, d4 = (qid - r * 48) * 4;
    int bm = r / kT, t = r - bm * kT;
    float4 acc = make_float4(cb[d4], cb[d4 + 1], cb[d4 + 2], cb[d4 + 3]);
    #pragma unroll
    for (int k = 0; k < kKM; k++) {
        int ts = dir ? (t + 3 - k) : (t + k - 3);
        if (ts < 0 || ts >= kT) continue;
        float4 v = *(const float4*)&xin[((size_t)bm * kT + ts) * kD + d4];
        acc.x += v.x * cw[(d4 + 0) * kKM + k];
        acc.y += v.y * cw[(d4 + 1) * kKM + k];
        acc.z += v.z * cw[(d4 + 2) * kKM + k];
        acc.w += v.w * cw[(d4 + 3) * kKM + k];
    }
    float4 o = make_float4(silu_f(acc.x), silu_f(acc.y), silu_f(acc.z), silu_f(acc.w));
    *(float4*)&xc[(size_t)r * kD + d4] = o;
}

// ---------------- mamba x-proj GEMM: [51400x192] @ [192x48pad] ----------------
// same structure as outproj_gemm; per-thread 8 rows x 3 cols.
__global__ __launch_bounds__(128)
void xpproj_gemm(const float* __restrict__ xc, float* __restrict__ dbl,
                 const float* __restrict__ wpx) {
    __shared__ float Al[192 * 64];  // 48 KiB
    int r0 = blockIdx.x * 64;
    int tid = threadIdx.x;
    for (int i = tid; i < 192 * 64; i += 128) {
        int m = i & 63, h = i >> 6;
        int r = r0 + m; if (r >= kROWS) r = kROWS - 1;
        Al[h * 64 + m] = xc[(size_t)r * kD + h];
    }
    __syncthreads();
    int rt = tid >> 4, ct = tid & 15;
    const float* bp = wpx + ct * 3;
    float acc[8][3];
    #pragma unroll
    for (int i = 0; i < 8; i++)
        #pragma unroll
        for (int j = 0; j < 3; j++) acc[i][j] = 0.f;
    for (int h = 0; h < 192; h++) {
        float4 a0 = *(const float4*)&Al[h * 64 + rt * 8];
        float4 a1 = *(const float4*)&Al[h * 64 + rt * 8 + 4];
        float b0 = bp[h * kDBLP], b1 = bp[h * kDBLP + 1], b2 = bp[h * kDBLP + 2];
        float ar[8] = {a0.x, a0.y, a0.z, a0.w, a1.x, a1.y, a1.z, a1.w};
        #pragma unroll
        for (int i = 0; i < 8; i++) {
            acc[i][0] += ar[i] * b0;
            acc[i][1] += ar[i] * b1;
            acc[i][2] += ar[i] * b2;
        }
    }
    int cbase = ct * 3;
    #pragma unroll
    for (int i = 0; i < 8; i++) {
        int r = r0 + rt * 8 + i;
        if (r >= kROWS) break;
        #pragma unroll
        for (int j = 0; j < 3; j++) {
            int c = cbase + j;
            if (c < kDBL) dbl[(size_t)r * kDBL + c] = acc[i][j];
        }
    }
}

// ---------------- mamba selective scan (dir: 0 fwd, 1 bwd over t) ----------------
__global__ void scan_kernel(const float* __restrict__ dbl, const float* __restrict__ z,
                            float* __restrict__ xcy,
                            const float* __restrict__ A_log, const float* __restrict__ dtw,
                            const float* __restrict__ dtb, const float* __restrict__ Dp, int dir) {
    int bm = blockIdx.x;
    int d = threadIdx.x;
    float A[kN], hst[kN], dw[kR];
    for (int n = 0; n < kN; n++) { A[n] = -__expf(A_log[d * kN + n]); hst[n] = 0.f; }
    for (int r = 0; r < kR; r++) dw[r] = dtw[d * kR + r];
    float db = dtb[d], Dv = Dp[d];
    for (int i = 0; i < kT; i++) {
        int t = dir ? (kT - 1 - i) : i;
        size_t rb = (size_t)(bm * kT + t);
        const float* dr = dbl + rb * kDBL;
        float s = db;
        #pragma unroll
        for (int r = 0; r < kR; r++) s += dr[r] * dw[r];
        float dt = softplus_f(s);
        float xv = xcy[rb * kD + d];
        float dtx = dt * xv;
        float y = 0.f;
        #pragma unroll
        for (int n = 0; n < kN; n++) {
            hst[n] = __expf(dt * A[n]) * hst[n] + dtx * dr[kR + n];
            y += hst[n] * dr[kR + kN + n];
        }
        float zv = z[rb * kD + d];
        xcy[rb * kD + d] = (y + xv * Dv) * silu_f(zv);
    }
}

extern "C" void kernel_launch(void* const* d_in, const int* in_sizes, int n_in,
                              void* d_out, int out_size, void* d_ws, size_t ws_size,
                              hipStream_t stream) {
    const float* x       = (const float*)d_in[0];
    const float* ln1_g   = (const float*)d_in[1];
    const float* ln1_b   = (const float*)d_in[2];
    const float* conv1_w = (const float*)d_in[3];
    const float* conv1_b = (const float*)d_in[4];
    const float* prelu1  = (const float*)d_in[5];
    const float* lnf_g   = (const float*)d_in[6];
    const float* lnf_b   = (const float*)d_in[7];
    const float* sq_w    = (const float*)d_in[8];
    const float* sq_b    = (const float*)d_in[9];
    const float* full_w  = (const float*)d_in[10];
    const float* full_b  = (const float*)d_in[11];
    const float* unsq_w  = (const float*)d_in[12];
    const float* unsq_b  = (const float*)d_in[13];
    const float* ln2_g   = (const float*)d_in[14];
    const float* ln2_b   = (const float*)d_in[15];
    const float* conv2_w = (const float*)d_in[16];
    const float* conv2_b = (const float*)d_in[17];
    const float* prelu2  = (const float*)d_in[18];
    const float* lnm_g   = (const float*)d_in[19];
    const float* lnm_b   = (const float*)d_in[20];

    float* ws   = (float*)d_ws;
    float* xbuf = ws;
    float* xn   = ws + (size_t)kNX;
    float* bufA = ws + 2 * (size_t)kNX;          // kNM: ln-out / xin / dbl
    float* bufB = bufA + (size_t)kNM;            // kNM: s1 / z
    float* bufC = bufB + (size_t)kNM;            // kNM: s2 / xc / ymid
    float* wTs  = bufC + (size_t)kNM;
    float* in_wT[2]  = { wTs, wTs + 2 * kD * kH };                  // [96][384]
    float* out_wp[2] = { wTs + 2 * (2 * kD * kH),
                         wTs + 2 * (2 * kD * kH) + kD * 128 };      // [192][128]
    float* xp_wp[2]  = { wTs + 2 * (2 * kD * kH) + 2 * kD * 128,
                         wTs + 2 * (2 * kD * kH) + 2 * kD * 128 + kD * kDBLP }; // [192][48]

    for (int dir = 0; dir < 2; dir++) {
        int wi = 21 + dir * 9;
        const float* in_w  = (const float*)d_in[wi + 0];
        const float* xp_w  = (const float*)d_in[wi + 3];
        const float* out_w = (const float*)d_in[wi + 8];
        transpose_kernel<<<(2 * kD * kH + 255) / 256, 256, 0, stream>>>(in_w, in_wT[dir], 2 * kD, kH);
        outpad_kernel<<<(kD * 128 + 255) / 256, 256, 0, stream>>>(out_w, out_wp[dir]);
        xppad_kernel<<<(kD * kDBLP + 255) / 256, 256, 0, stream>>>(xp_w, xp_wp[dir]);
    }

    int lnGrid = (kROWS + 3) / 4;
    int nxGrid = (kNX + 255) / 256;
    dim3 fcGrid(kG, kT, kB);

    // stage 1: x = x + fconv(x)
    ln_kernel<<<lnGrid, 256, 0, stream>>>(x, bufA, ln1_g, ln1_b, kROWS);
    fconv_kernel<<<fcGrid, 256, 0, stream>>>(bufA, x, xbuf, conv1_w, conv1_b, prelu1);

    // stage 2: x = x + full(x)
    ln_kernel<<<lnGrid, 256, 0, stream>>>(xbuf, bufA, lnf_g, lnf_b, kROWS);
    squeeze_kernel<<<dim3(kB * kT, (kF + 63) / 64), 64, 0, stream>>>(bufA, bufB, sq_w, sq_b);
    fullmat_gemm<<<dim3(5, 4, kS), 256, 0, stream>>>(bufB, bufC, full_w, full_b);
    unsqueeze_kernel<<<nxGrid, 256, 0, stream>>>(bufC, xbuf, unsq_w, unsq_b);

    // stage 3: x = x + fconv(x)  (in-place: resid == out)
    ln_kernel<<<lnGrid, 256, 0, stream>>>(xbuf, bufA, ln2_g, ln2_b, kROWS);
    fconv_kernel<<<fcGrid, 256, 0, stream>>>(bufA, xbuf, xbuf, conv2_w, conv2_b, prelu2);

    // mamba input: xn = LN(x)
    ln_kernel<<<lnGrid, 256, 0, stream>>>(xbuf, xn, lnm_g, lnm_b, kROWS);

    for (int dir = 0; dir < 2; dir++) {
        int wi = 21 + dir * 9;
        const float* conv_w = (const float*)d_in[wi + 1];
        const float* conv_b = (const float*)d_in[wi + 2];
        const float* dt_w   = (const float*)d_in[wi + 4];
        const float* dt_b   = (const float*)d_in[wi + 5];
        const float* A_log  = (const float*)d_in[wi + 6];
        const float* Dp     = (const float*)d_in[wi + 7];

        inproj_gemm<<<dim3((kROWS + 63) / 64, 3), 128, 0, stream>>>(xn, in_wT[dir], bufA, bufB);
        mconv_kernel<<<(kROWS * 48 + 255) / 256, 256, 0, stream>>>(bufA, bufC, conv_w, conv_b, dir);
        xpproj_gemm<<<(kROWS + 63) / 64, 128, 0, stream>>>(bufC, bufA, xp_wp[dir]);
        scan_kernel<<<kBM, kD, 0, stream>>>(bufA, bufB, bufC, A_log, dt_w, dt_b, Dp, dir);
        outproj_gemm<<<(kROWS + 63) / 64, 128, 0, stream>>>(bufC, out_wp[dir], xbuf, (float*)d_out, dir);
    }
}